// Round 6
// baseline (1209.494 us; speedup 1.0000x reference)
//
#include <hip/hip_runtime.h>

// N = 100000 nodes, E = 1600000 edges, IN=128, HID=128, LAT=64
// edge_index arrives on device as int32 (harness converts integer inputs).
//
// R5 structure + ONE change: dense phases register-tiled 4ch x 4rows (sage1/dec)
// and 4ch x 2rows (sage2) per thread -> 4x fewer LDS read instructions,
// float4 output stores. Gather and CSR build identical to R5.

// ---------------- degree (int): deg[dst]++ ----------------
__global__ void k_deg(const int* __restrict__ dst, int* __restrict__ deg, int E, int nNodes) {
    int i = blockIdx.x * blockDim.x + threadIdx.x;
    if (i < E) {
        unsigned d = (unsigned)dst[i];
        if (d < (unsigned)nNodes) atomicAdd(&deg[d], 1);
    }
}

// ---------------- scan stage 1 ----------------
__global__ void k_scan1(const int* __restrict__ deg, int* __restrict__ off,
                        int* __restrict__ bs, int nNodes) {
    __shared__ int tmp[256];
    int t = threadIdx.x;
    int i = blockIdx.x * 256 + t;
    int v = (i < nNodes) ? deg[i] : 0;
    tmp[t] = v;
    __syncthreads();
    for (int d = 1; d < 256; d <<= 1) {
        int add = (t >= d) ? tmp[t - d] : 0;
        __syncthreads();
        tmp[t] += add;
        __syncthreads();
    }
    if (i < nNodes) off[i] = tmp[t] - v;
    if (t == 255) bs[blockIdx.x] = tmp[255];
}

// ---------------- scan stage 2 (1 block) ----------------
__global__ void k_scan2(int* __restrict__ bs, int nb) {
    __shared__ int tmp[512];
    int t = threadIdx.x;
    int carry = 0;
    for (int start = 0; start < nb; start += 512) {
        int i = start + t;
        int v = (i < nb) ? bs[i] : 0;
        tmp[t] = v;
        __syncthreads();
        for (int d = 1; d < 512; d <<= 1) {
            int add = (t >= d) ? tmp[t - d] : 0;
            __syncthreads();
            tmp[t] += add;
            __syncthreads();
        }
        int incl = tmp[t];
        if (i < nb) bs[i] = incl - v + carry;
        int total = tmp[511];
        __syncthreads();
        carry += total;
    }
}

// ---------------- scan stage 3 ----------------
__global__ void k_scan3(int* __restrict__ off, const int* __restrict__ bs, int nNodes) {
    int i = blockIdx.x * 256 + threadIdx.x;
    if (i < nNodes) off[i] += bs[blockIdx.x];
}

// ---------------- CSR fill ----------------
__global__ void k_fill(const int* __restrict__ src, const int* __restrict__ dst,
                       const int* __restrict__ off, int* __restrict__ cur,
                       int* __restrict__ adj, int E, int nNodes) {
    int i = blockIdx.x * blockDim.x + threadIdx.x;
    if (i < E) {
        unsigned d = (unsigned)dst[i];
        unsigned s = (unsigned)src[i];
        if (d < (unsigned)nNodes && s < (unsigned)nNodes) {
            int pos = atomicAdd(&cur[d], 1);
            adj[off[d] + pos] = (int)s;
        }
    }
}

// ---------------- gather-mean helper (R5 verbatim) ----------------
__device__ __forceinline__ void gather_rows(const float* __restrict__ feat,
                                            const int* __restrict__ adj,
                                            const int* __restrict__ off,
                                            const int* __restrict__ deg,
                                            float (*ms)[128],
                                            int base, int nNodes, int tid) {
    int w = tid >> 6, lane = tid & 63;
    int half = lane >> 5, l32 = lane & 31;
    const float4* feat4 = (const float4*)feat;
    for (int r = w * 8; r < w * 8 + 8; ++r) {
        int n = base + r;
        float4 a = make_float4(0.f, 0.f, 0.f, 0.f);
        float inv = 1.f;
        if (n < nNodes) {
            int o0 = off[n];
            int dg = deg[n];
            int o1 = o0 + dg;
            int k = o0 + half;
            for (; k + 6 < o1; k += 8) {
                int s0 = adj[k + 0];
                int s1 = adj[k + 2];
                int s2 = adj[k + 4];
                int s3 = adj[k + 6];
                float4 v0 = feat4[(long long)s0 * 32 + l32];
                float4 v1 = feat4[(long long)s1 * 32 + l32];
                float4 v2 = feat4[(long long)s2 * 32 + l32];
                float4 v3 = feat4[(long long)s3 * 32 + l32];
                a.x += v0.x + v1.x + v2.x + v3.x;
                a.y += v0.y + v1.y + v2.y + v3.y;
                a.z += v0.z + v1.z + v2.z + v3.z;
                a.w += v0.w + v1.w + v2.w + v3.w;
            }
            for (; k < o1; k += 2) {
                int s = adj[k];
                float4 v = feat4[(long long)s * 32 + l32];
                a.x += v.x; a.y += v.y; a.z += v.z; a.w += v.w;
            }
            inv = 1.f / fmaxf((float)dg, 1.f);
        }
        a.x += __shfl_xor(a.x, 32);
        a.y += __shfl_xor(a.y, 32);
        a.z += __shfl_xor(a.z, 32);
        a.w += __shfl_xor(a.w, 32);
        if (half == 0) {
            a.x *= inv; a.y *= inv; a.z *= inv; a.w *= inv;
            ((float4*)&ms[r][0])[l32] = a;
        }
    }
}

// ---------------- fused gather + SAGE layer 1 ----------------
// 32 nodes/block, 256 threads. Dense: 32 ch-groups (4 ch) x 8 row-groups (4 rows).
__launch_bounds__(256)
__global__ void k_sage1(const float* __restrict__ x,
                        const int* __restrict__ adj, const int* __restrict__ off,
                        const int* __restrict__ deg,
                        const float* __restrict__ Wl, const float* __restrict__ bl,
                        const float* __restrict__ Wr,
                        float* __restrict__ h, int nNodes) {
    __shared__ float xs[32][128];
    __shared__ float ms[32][128];
    int tid = threadIdx.x;
    int base = blockIdx.x * 32;

    for (int i = tid; i < 32 * 32; i += 256) {
        int row = i >> 5, col4 = i & 31;
        int n = base + row;
        float4 xv = make_float4(0.f, 0.f, 0.f, 0.f);
        if (n < nNodes) xv = ((const float4*)x)[(long long)n * 32 + col4];
        ((float4*)&xs[row][0])[col4] = xv;
    }

    gather_rows(x, adj, off, deg, ms, base, nNodes, tid);
    __syncthreads();

    int cg = tid & 31;    // channels cg*4 .. cg*4+3
    int rg = tid >> 5;    // rows rg*4 .. rg*4+3
    float acc[4][4];
#pragma unroll
    for (int rr = 0; rr < 4; ++rr)
#pragma unroll
        for (int cc = 0; cc < 4; ++cc) acc[rr][cc] = 0.f;

    for (int kc = 0; kc < 32; ++kc) {
        float4 w_r[4], w_l[4];
#pragma unroll
        for (int cc = 0; cc < 4; ++cc) {
            w_r[cc] = ((const float4*)&Wr[(cg * 4 + cc) * 128])[kc];
            w_l[cc] = ((const float4*)&Wl[(cg * 4 + cc) * 128])[kc];
        }
#pragma unroll
        for (int rr = 0; rr < 4; ++rr) {
            float4 xv = ((const float4*)&xs[rg * 4 + rr][0])[kc];
            float4 mv = ((const float4*)&ms[rg * 4 + rr][0])[kc];
#pragma unroll
            for (int cc = 0; cc < 4; ++cc) {
                acc[rr][cc] += xv.x * w_r[cc].x + xv.y * w_r[cc].y
                             + xv.z * w_r[cc].z + xv.w * w_r[cc].w
                             + mv.x * w_l[cc].x + mv.y * w_l[cc].y
                             + mv.z * w_l[cc].z + mv.w * w_l[cc].w;
            }
        }
    }
    float4 b4 = ((const float4*)bl)[cg];
#pragma unroll
    for (int rr = 0; rr < 4; ++rr) {
        int n = base + rg * 4 + rr;
        if (n < nNodes) {
            float4 o;
            o.x = fmaxf(acc[rr][0] + b4.x, 0.f);
            o.y = fmaxf(acc[rr][1] + b4.y, 0.f);
            o.z = fmaxf(acc[rr][2] + b4.z, 0.f);
            o.w = fmaxf(acc[rr][3] + b4.w, 0.f);
            ((float4*)h)[(long long)n * 32 + cg] = o;
        }
    }
}

// ---------------- fused gather + SAGE layer 2 (64 out ch, no relu) ----------------
// Dense: 16 ch-groups (4 ch) x 16 row-groups (2 rows).
__launch_bounds__(256)
__global__ void k_sage2(const float* __restrict__ hin,
                        const int* __restrict__ adj, const int* __restrict__ off,
                        const int* __restrict__ deg,
                        const float* __restrict__ Wl, const float* __restrict__ bl,
                        const float* __restrict__ Wr,
                        float* __restrict__ z, int nNodes) {
    __shared__ float xs[32][128];
    __shared__ float ms[32][128];
    int tid = threadIdx.x;
    int base = blockIdx.x * 32;

    for (int i = tid; i < 32 * 32; i += 256) {
        int row = i >> 5, col4 = i & 31;
        int n = base + row;
        float4 xv = make_float4(0.f, 0.f, 0.f, 0.f);
        if (n < nNodes) xv = ((const float4*)hin)[(long long)n * 32 + col4];
        ((float4*)&xs[row][0])[col4] = xv;
    }

    gather_rows(hin, adj, off, deg, ms, base, nNodes, tid);
    __syncthreads();

    int cg = tid & 15;    // channels cg*4 .. cg*4+3 (of 64)
    int rg = tid >> 4;    // rows rg*2 .. rg*2+1
    float acc[2][4];
#pragma unroll
    for (int rr = 0; rr < 2; ++rr)
#pragma unroll
        for (int cc = 0; cc < 4; ++cc) acc[rr][cc] = 0.f;

    for (int kc = 0; kc < 32; ++kc) {
        float4 w_r[4], w_l[4];
#pragma unroll
        for (int cc = 0; cc < 4; ++cc) {
            w_r[cc] = ((const float4*)&Wr[(cg * 4 + cc) * 128])[kc];
            w_l[cc] = ((const float4*)&Wl[(cg * 4 + cc) * 128])[kc];
        }
#pragma unroll
        for (int rr = 0; rr < 2; ++rr) {
            float4 xv = ((const float4*)&xs[rg * 2 + rr][0])[kc];
            float4 mv = ((const float4*)&ms[rg * 2 + rr][0])[kc];
#pragma unroll
            for (int cc = 0; cc < 4; ++cc) {
                acc[rr][cc] += xv.x * w_r[cc].x + xv.y * w_r[cc].y
                             + xv.z * w_r[cc].z + xv.w * w_r[cc].w
                             + mv.x * w_l[cc].x + mv.y * w_l[cc].y
                             + mv.z * w_l[cc].z + mv.w * w_l[cc].w;
            }
        }
    }
    float4 b4 = ((const float4*)bl)[cg];
#pragma unroll
    for (int rr = 0; rr < 2; ++rr) {
        int n = base + rg * 2 + rr;
        if (n < nNodes) {
            float4 o;
            o.x = acc[rr][0] + b4.x;
            o.y = acc[rr][1] + b4.y;
            o.z = acc[rr][2] + b4.z;
            o.w = acc[rr][3] + b4.w;
            ((float4*)z)[(long long)n * 16 + cg] = o;
        }
    }
}

// ---------------- decoder: out = z @ W_dec^T + b_dec ----------------
// Dense: 32 ch-groups (4 ch) x 8 row-groups (4 rows), K=64.
__launch_bounds__(256)
__global__ void k_dec(const float* __restrict__ z, const float* __restrict__ W,
                      const float* __restrict__ b,
                      float* __restrict__ out, int nNodes) {
    __shared__ float zs[32][64];
    int tid = threadIdx.x;
    int base = blockIdx.x * 32;

    for (int i = tid; i < 32 * 16; i += 256) {
        int row = i >> 4, col4 = i & 15;
        int n = base + row;
        float4 zv = make_float4(0.f, 0.f, 0.f, 0.f);
        if (n < nNodes) zv = ((const float4*)z)[(long long)n * 16 + col4];
        ((float4*)&zs[row][0])[col4] = zv;
    }
    __syncthreads();

    int cg = tid & 31;    // channels cg*4 .. cg*4+3
    int rg = tid >> 5;    // rows rg*4 .. rg*4+3
    float acc[4][4];
#pragma unroll
    for (int rr = 0; rr < 4; ++rr)
#pragma unroll
        for (int cc = 0; cc < 4; ++cc) acc[rr][cc] = 0.f;

    for (int kc = 0; kc < 16; ++kc) {
        float4 w4[4];
#pragma unroll
        for (int cc = 0; cc < 4; ++cc)
            w4[cc] = ((const float4*)&W[(cg * 4 + cc) * 64])[kc];
#pragma unroll
        for (int rr = 0; rr < 4; ++rr) {
            float4 zv = ((const float4*)&zs[rg * 4 + rr][0])[kc];
#pragma unroll
            for (int cc = 0; cc < 4; ++cc) {
                acc[rr][cc] += zv.x * w4[cc].x + zv.y * w4[cc].y
                             + zv.z * w4[cc].z + zv.w * w4[cc].w;
            }
        }
    }
    float4 b4 = ((const float4*)b)[cg];
#pragma unroll
    for (int rr = 0; rr < 4; ++rr) {
        int n = base + rg * 4 + rr;
        if (n < nNodes) {
            float4 o;
            o.x = acc[rr][0] + b4.x;
            o.y = acc[rr][1] + b4.y;
            o.z = acc[rr][2] + b4.z;
            o.w = acc[rr][3] + b4.w;
            ((float4*)out)[(long long)n * 32 + cg] = o;
        }
    }
}

extern "C" void kernel_launch(void* const* d_in, const int* in_sizes, int n_in,
                              void* d_out, int out_size, void* d_ws, size_t ws_size,
                              hipStream_t stream) {
    const float* x    = (const float*)d_in[0];
    const int*   ei   = (const int*)d_in[1];   // int32 on device
    const float* W1l  = (const float*)d_in[2];
    const float* b1l  = (const float*)d_in[3];
    const float* W1r  = (const float*)d_in[4];
    const float* W2l  = (const float*)d_in[5];
    const float* b2l  = (const float*)d_in[6];
    const float* W2r  = (const float*)d_in[7];
    const float* Wdec = (const float*)d_in[8];
    const float* bdec = (const float*)d_in[9];

    const int N = in_sizes[0] / 128;
    const int E = in_sizes[1] / 2;
    const int nb = (N + 255) / 256;

    const int* src = ei;
    const int* dst = ei + E;

    // ws layout (ints): adj[E] | deg[N] | cur[N] | off[N] | bs[nb]
    int* adj = (int*)d_ws;
    int* deg = adj + E;
    int* cur = deg + N;
    int* off = cur + N;
    int* bs  = off + N;

    hipMemsetAsync(deg, 0, (size_t)2 * N * sizeof(int), stream);

    k_deg  <<<(E + 255) / 256, 256, 0, stream>>>(dst, deg, E, N);
    k_scan1<<<nb, 256, 0, stream>>>(deg, off, bs, N);
    k_scan2<<<1, 512, 0, stream>>>(bs, nb);
    k_scan3<<<nb, 256, 0, stream>>>(off, bs, N);
    k_fill <<<(E + 255) / 256, 256, 0, stream>>>(src, dst, off, cur, adj, E, N);

    // d_out layout: x_recon [N*128] then z [N*64]; park h in x_recon region
    float* outp = (float*)d_out;
    float* h    = outp;
    float* z    = outp + (long long)N * 128;
    float* xrec = outp;

    const int nblk = (N + 31) / 32;
    k_sage1<<<nblk, 256, 0, stream>>>(x, adj, off, deg, W1l, b1l, W1r, h, N);
    k_sage2<<<nblk, 256, 0, stream>>>(h, adj, off, deg, W2l, b2l, W2r, z, N);
    k_dec  <<<nblk, 256, 0, stream>>>(z, Wdec, bdec, xrec, N);
}

// Round 7
// 1035.864 us; speedup vs baseline: 1.1676x; 1.1676x over previous
//
#include <hip/hip_runtime.h>

// N = 100000 nodes, E = 1600000 edges, IN=128, HID=128, LAT=64
// edge_index arrives on device as int32 (harness converts integer inputs).
//
// R5 structure. Change vs R5 (fixing R6's mistake): sage dense phases use
// 4ch x 4row register tiles with weight k-chunks STAGED IN LDS (read from
// global once per block, coalesced) instead of per-thread scattered global
// weight loads. Channels per thread strided by 32 -> coalesced stores,
// conflict-balanced LDS weight reads. Gather/CSR/k_dec are R5 verbatim.

// ---------------- degree (int): deg[dst]++ ----------------
__global__ void k_deg(const int* __restrict__ dst, int* __restrict__ deg, int E, int nNodes) {
    int i = blockIdx.x * blockDim.x + threadIdx.x;
    if (i < E) {
        unsigned d = (unsigned)dst[i];
        if (d < (unsigned)nNodes) atomicAdd(&deg[d], 1);
    }
}

// ---------------- scan stage 1 ----------------
__global__ void k_scan1(const int* __restrict__ deg, int* __restrict__ off,
                        int* __restrict__ bs, int nNodes) {
    __shared__ int tmp[256];
    int t = threadIdx.x;
    int i = blockIdx.x * 256 + t;
    int v = (i < nNodes) ? deg[i] : 0;
    tmp[t] = v;
    __syncthreads();
    for (int d = 1; d < 256; d <<= 1) {
        int add = (t >= d) ? tmp[t - d] : 0;
        __syncthreads();
        tmp[t] += add;
        __syncthreads();
    }
    if (i < nNodes) off[i] = tmp[t] - v;
    if (t == 255) bs[blockIdx.x] = tmp[255];
}

// ---------------- scan stage 2 (1 block) ----------------
__global__ void k_scan2(int* __restrict__ bs, int nb) {
    __shared__ int tmp[512];
    int t = threadIdx.x;
    int carry = 0;
    for (int start = 0; start < nb; start += 512) {
        int i = start + t;
        int v = (i < nb) ? bs[i] : 0;
        tmp[t] = v;
        __syncthreads();
        for (int d = 1; d < 512; d <<= 1) {
            int add = (t >= d) ? tmp[t - d] : 0;
            __syncthreads();
            tmp[t] += add;
            __syncthreads();
        }
        int incl = tmp[t];
        if (i < nb) bs[i] = incl - v + carry;
        int total = tmp[511];
        __syncthreads();
        carry += total;
    }
}

// ---------------- scan stage 3 ----------------
__global__ void k_scan3(int* __restrict__ off, const int* __restrict__ bs, int nNodes) {
    int i = blockIdx.x * 256 + threadIdx.x;
    if (i < nNodes) off[i] += bs[blockIdx.x];
}

// ---------------- CSR fill ----------------
__global__ void k_fill(const int* __restrict__ src, const int* __restrict__ dst,
                       const int* __restrict__ off, int* __restrict__ cur,
                       int* __restrict__ adj, int E, int nNodes) {
    int i = blockIdx.x * blockDim.x + threadIdx.x;
    if (i < E) {
        unsigned d = (unsigned)dst[i];
        unsigned s = (unsigned)src[i];
        if (d < (unsigned)nNodes && s < (unsigned)nNodes) {
            int pos = atomicAdd(&cur[d], 1);
            adj[off[d] + pos] = (int)s;
        }
    }
}

// ---------------- gather-mean helper (R5 verbatim) ----------------
__device__ __forceinline__ void gather_rows(const float* __restrict__ feat,
                                            const int* __restrict__ adj,
                                            const int* __restrict__ off,
                                            const int* __restrict__ deg,
                                            float (*ms)[128],
                                            int base, int nNodes, int tid) {
    int w = tid >> 6, lane = tid & 63;
    int half = lane >> 5, l32 = lane & 31;
    const float4* feat4 = (const float4*)feat;
    for (int r = w * 8; r < w * 8 + 8; ++r) {
        int n = base + r;
        float4 a = make_float4(0.f, 0.f, 0.f, 0.f);
        float inv = 1.f;
        if (n < nNodes) {
            int o0 = off[n];
            int dg = deg[n];
            int o1 = o0 + dg;
            int k = o0 + half;
            for (; k + 6 < o1; k += 8) {
                int s0 = adj[k + 0];
                int s1 = adj[k + 2];
                int s2 = adj[k + 4];
                int s3 = adj[k + 6];
                float4 v0 = feat4[(long long)s0 * 32 + l32];
                float4 v1 = feat4[(long long)s1 * 32 + l32];
                float4 v2 = feat4[(long long)s2 * 32 + l32];
                float4 v3 = feat4[(long long)s3 * 32 + l32];
                a.x += v0.x + v1.x + v2.x + v3.x;
                a.y += v0.y + v1.y + v2.y + v3.y;
                a.z += v0.z + v1.z + v2.z + v3.z;
                a.w += v0.w + v1.w + v2.w + v3.w;
            }
            for (; k < o1; k += 2) {
                int s = adj[k];
                float4 v = feat4[(long long)s * 32 + l32];
                a.x += v.x; a.y += v.y; a.z += v.z; a.w += v.w;
            }
            inv = 1.f / fmaxf((float)dg, 1.f);
        }
        a.x += __shfl_xor(a.x, 32);
        a.y += __shfl_xor(a.y, 32);
        a.z += __shfl_xor(a.z, 32);
        a.w += __shfl_xor(a.w, 32);
        if (half == 0) {
            a.x *= inv; a.y *= inv; a.z *= inv; a.w *= inv;
            ((float4*)&ms[r][0])[l32] = a;
        }
    }
}

// ---------------- fused gather + SAGE layer 1 ----------------
// 32 nodes/block, 256 threads. Dense: thread = (cg: 32) x (rg: 8);
// channels {cg, cg+32, cg+64, cg+96}, rows rg*4..rg*4+3.
// Weight k-chunks (32 k) staged in LDS, x-pass then m-pass per chunk.
__launch_bounds__(256)
__global__ void k_sage1(const float* __restrict__ x,
                        const int* __restrict__ adj, const int* __restrict__ off,
                        const int* __restrict__ deg,
                        const float* __restrict__ Wl, const float* __restrict__ bl,
                        const float* __restrict__ Wr,
                        float* __restrict__ h, int nNodes) {
    __shared__ float xs[32][128];
    __shared__ float ms[32][128];
    __shared__ float4 wst[128][9];   // [out-ch][8 float4 of k-chunk + pad]
    int tid = threadIdx.x;
    int base = blockIdx.x * 32;

    for (int i = tid; i < 32 * 32; i += 256) {
        int row = i >> 5, col4 = i & 31;
        int n = base + row;
        float4 xv = make_float4(0.f, 0.f, 0.f, 0.f);
        if (n < nNodes) xv = ((const float4*)x)[(long long)n * 32 + col4];
        ((float4*)&xs[row][0])[col4] = xv;
    }

    gather_rows(x, adj, off, deg, ms, base, nNodes, tid);

    int cg = tid & 31;
    int rg = tid >> 5;
    float acc[4][4];
#pragma unroll
    for (int rr = 0; rr < 4; ++rr)
#pragma unroll
        for (int cc = 0; cc < 4; ++cc) acc[rr][cc] = 0.f;

    const float4* Wr4 = (const float4*)Wr;
    const float4* Wl4 = (const float4*)Wl;

    for (int chunk = 0; chunk < 4; ++chunk) {
        int kb = chunk * 8;                      // float4 granule base
        // ---- stage Wr chunk ----
        __syncthreads();                         // also covers gather->dense on chunk 0
        for (int j = tid; j < 128 * 8; j += 256) {
            int ch = j >> 3, f = j & 7;
            wst[ch][f] = Wr4[ch * 32 + kb + f];
        }
        __syncthreads();
#pragma unroll
        for (int f = 0; f < 8; ++f) {
            float4 w[4];
#pragma unroll
            for (int cc = 0; cc < 4; ++cc) w[cc] = wst[cg + 32 * cc][f];
#pragma unroll
            for (int rr = 0; rr < 4; ++rr) {
                float4 xv = ((const float4*)&xs[rg * 4 + rr][0])[kb + f];
#pragma unroll
                for (int cc = 0; cc < 4; ++cc)
                    acc[rr][cc] += xv.x * w[cc].x + xv.y * w[cc].y
                                 + xv.z * w[cc].z + xv.w * w[cc].w;
            }
        }
        // ---- stage Wl chunk ----
        __syncthreads();
        for (int j = tid; j < 128 * 8; j += 256) {
            int ch = j >> 3, f = j & 7;
            wst[ch][f] = Wl4[ch * 32 + kb + f];
        }
        __syncthreads();
#pragma unroll
        for (int f = 0; f < 8; ++f) {
            float4 w[4];
#pragma unroll
            for (int cc = 0; cc < 4; ++cc) w[cc] = wst[cg + 32 * cc][f];
#pragma unroll
            for (int rr = 0; rr < 4; ++rr) {
                float4 mv = ((const float4*)&ms[rg * 4 + rr][0])[kb + f];
#pragma unroll
                for (int cc = 0; cc < 4; ++cc)
                    acc[rr][cc] += mv.x * w[cc].x + mv.y * w[cc].y
                                 + mv.z * w[cc].z + mv.w * w[cc].w;
            }
        }
    }

#pragma unroll
    for (int rr = 0; rr < 4; ++rr) {
        int n = base + rg * 4 + rr;
        if (n < nNodes) {
#pragma unroll
            for (int cc = 0; cc < 4; ++cc) {
                int ch = cg + 32 * cc;
                h[(long long)n * 128 + ch] = fmaxf(acc[rr][cc] + bl[ch], 0.f);
            }
        }
    }
}

// ---------------- fused gather + SAGE layer 2 (64 out ch, no relu) ----------------
// Dense: thread = (cg: 32) x (rg: 8); channels {cg, cg+32}, rows rg*4..+3.
__launch_bounds__(256)
__global__ void k_sage2(const float* __restrict__ hin,
                        const int* __restrict__ adj, const int* __restrict__ off,
                        const int* __restrict__ deg,
                        const float* __restrict__ Wl, const float* __restrict__ bl,
                        const float* __restrict__ Wr,
                        float* __restrict__ z, int nNodes) {
    __shared__ float xs[32][128];
    __shared__ float ms[32][128];
    __shared__ float4 wst[64][9];    // [out-ch][8 float4 + pad]
    int tid = threadIdx.x;
    int base = blockIdx.x * 32;

    for (int i = tid; i < 32 * 32; i += 256) {
        int row = i >> 5, col4 = i & 31;
        int n = base + row;
        float4 xv = make_float4(0.f, 0.f, 0.f, 0.f);
        if (n < nNodes) xv = ((const float4*)hin)[(long long)n * 32 + col4];
        ((float4*)&xs[row][0])[col4] = xv;
    }

    gather_rows(hin, adj, off, deg, ms, base, nNodes, tid);

    int cg = tid & 31;
    int rg = tid >> 5;
    float acc[4][2];
#pragma unroll
    for (int rr = 0; rr < 4; ++rr)
#pragma unroll
        for (int cc = 0; cc < 2; ++cc) acc[rr][cc] = 0.f;

    const float4* Wr4 = (const float4*)Wr;
    const float4* Wl4 = (const float4*)Wl;

    for (int chunk = 0; chunk < 4; ++chunk) {
        int kb = chunk * 8;
        // ---- stage Wr chunk (64 x 8 float4 = 512) ----
        __syncthreads();
        for (int j = tid; j < 64 * 8; j += 256) {
            int ch = j >> 3, f = j & 7;
            wst[ch][f] = Wr4[ch * 32 + kb + f];
        }
        __syncthreads();
#pragma unroll
        for (int f = 0; f < 8; ++f) {
            float4 w[2];
#pragma unroll
            for (int cc = 0; cc < 2; ++cc) w[cc] = wst[cg + 32 * cc][f];
#pragma unroll
            for (int rr = 0; rr < 4; ++rr) {
                float4 xv = ((const float4*)&xs[rg * 4 + rr][0])[kb + f];
#pragma unroll
                for (int cc = 0; cc < 2; ++cc)
                    acc[rr][cc] += xv.x * w[cc].x + xv.y * w[cc].y
                                 + xv.z * w[cc].z + xv.w * w[cc].w;
            }
        }
        // ---- stage Wl chunk ----
        __syncthreads();
        for (int j = tid; j < 64 * 8; j += 256) {
            int ch = j >> 3, f = j & 7;
            wst[ch][f] = Wl4[ch * 32 + kb + f];
        }
        __syncthreads();
#pragma unroll
        for (int f = 0; f < 8; ++f) {
            float4 w[2];
#pragma unroll
            for (int cc = 0; cc < 2; ++cc) w[cc] = wst[cg + 32 * cc][f];
#pragma unroll
            for (int rr = 0; rr < 4; ++rr) {
                float4 mv = ((const float4*)&ms[rg * 4 + rr][0])[kb + f];
#pragma unroll
                for (int cc = 0; cc < 2; ++cc)
                    acc[rr][cc] += mv.x * w[cc].x + mv.y * w[cc].y
                                 + mv.z * w[cc].z + mv.w * w[cc].w;
            }
        }
    }

#pragma unroll
    for (int rr = 0; rr < 4; ++rr) {
        int n = base + rg * 4 + rr;
        if (n < nNodes) {
#pragma unroll
            for (int cc = 0; cc < 2; ++cc) {
                int ch = cg + 32 * cc;
                z[(long long)n * 64 + ch] = acc[rr][cc] + bl[ch];
            }
        }
    }
}

// ---------------- decoder: out = z @ W_dec^T + b_dec (R5 verbatim) ----------------
__launch_bounds__(256)
__global__ void k_dec(const float* __restrict__ z, const float* __restrict__ W,
                      const float* __restrict__ b,
                      float* __restrict__ out, int nNodes) {
    __shared__ float zs[32][64];
    int tid = threadIdx.x;
    int base = blockIdx.x * 32;

    for (int i = tid; i < 32 * 16; i += 256) {
        int row = i >> 4, col4 = i & 15;
        int n = base + row;
        float4 zv = make_float4(0.f, 0.f, 0.f, 0.f);
        if (n < nNodes) zv = ((const float4*)z)[(long long)n * 16 + col4];
        ((float4*)&zs[row][0])[col4] = zv;
    }
    __syncthreads();

    int ch = tid & 127;
    int g  = tid >> 7;
    float acc[16];
#pragma unroll
    for (int i = 0; i < 16; ++i) acc[i] = 0.f;

    const float4* w = (const float4*)&W[ch * 64];
    for (int kc = 0; kc < 16; ++kc) {
        float4 w4 = w[kc];
#pragma unroll
        for (int i = 0; i < 16; ++i) {
            int row = g * 16 + i;
            float4 zv = ((const float4*)&zs[row][0])[kc];
            acc[i] += zv.x * w4.x + zv.y * w4.y + zv.z * w4.z + zv.w * w4.w;
        }
    }
    float bias = b[ch];
#pragma unroll
    for (int i = 0; i < 16; ++i) {
        int n = base + g * 16 + i;
        if (n < nNodes) out[(long long)n * 128 + ch] = acc[i] + bias;
    }
}

extern "C" void kernel_launch(void* const* d_in, const int* in_sizes, int n_in,
                              void* d_out, int out_size, void* d_ws, size_t ws_size,
                              hipStream_t stream) {
    const float* x    = (const float*)d_in[0];
    const int*   ei   = (const int*)d_in[1];   // int32 on device
    const float* W1l  = (const float*)d_in[2];
    const float* b1l  = (const float*)d_in[3];
    const float* W1r  = (const float*)d_in[4];
    const float* W2l  = (const float*)d_in[5];
    const float* b2l  = (const float*)d_in[6];
    const float* W2r  = (const float*)d_in[7];
    const float* Wdec = (const float*)d_in[8];
    const float* bdec = (const float*)d_in[9];

    const int N = in_sizes[0] / 128;
    const int E = in_sizes[1] / 2;
    const int nb = (N + 255) / 256;

    const int* src = ei;
    const int* dst = ei + E;

    // ws layout (ints): adj[E] | deg[N] | cur[N] | off[N] | bs[nb]
    int* adj = (int*)d_ws;
    int* deg = adj + E;
    int* cur = deg + N;
    int* off = cur + N;
    int* bs  = off + N;

    hipMemsetAsync(deg, 0, (size_t)2 * N * sizeof(int), stream);

    k_deg  <<<(E + 255) / 256, 256, 0, stream>>>(dst, deg, E, N);
    k_scan1<<<nb, 256, 0, stream>>>(deg, off, bs, N);
    k_scan2<<<1, 512, 0, stream>>>(bs, nb);
    k_scan3<<<nb, 256, 0, stream>>>(off, bs, N);
    k_fill <<<(E + 255) / 256, 256, 0, stream>>>(src, dst, off, cur, adj, E, N);

    // d_out layout: x_recon [N*128] then z [N*64]; park h in x_recon region
    float* outp = (float*)d_out;
    float* h    = outp;
    float* z    = outp + (long long)N * 128;
    float* xrec = outp;

    const int nblk = (N + 31) / 32;
    k_sage1<<<nblk, 256, 0, stream>>>(x, adj, off, deg, W1l, b1l, W1r, h, N);
    k_sage2<<<nblk, 256, 0, stream>>>(h, adj, off, deg, W2l, b2l, W2r, z, N);
    k_dec  <<<nblk, 256, 0, stream>>>(z, Wdec, bdec, xrec, N);
}

// Round 8
// 662.019 us; speedup vs baseline: 1.8270x; 1.5647x over previous
//
#include <hip/hip_runtime.h>

// N = 100000 nodes, E = 1600000 edges, IN=128, HID=128, LAT=64
// edge_index arrives on device as int32 (harness converts integer inputs).
//
// R5 gather/CSR + NEW dense: weights pre-transposed to [k][ch] in ws, so the
// dense phase uses 4ch x 4row register tiles with COALESCED global weight
// loads (VMEM pipe) and 4x fewer LDS reads than R5. No extra barriers.

// ---------------- weight transpose: Wt[k][c] = W[c][k] ----------------
__global__ void k_tw(const float* __restrict__ W, float* __restrict__ Wt, int K, int OC) {
    int i = blockIdx.x * blockDim.x + threadIdx.x;
    if (i < K * OC) {
        int k = i / OC, c = i % OC;
        Wt[i] = W[c * K + k];
    }
}

// ---------------- degree (int): deg[dst]++ ----------------
__global__ void k_deg(const int* __restrict__ dst, int* __restrict__ deg, int E, int nNodes) {
    int i = blockIdx.x * blockDim.x + threadIdx.x;
    if (i < E) {
        unsigned d = (unsigned)dst[i];
        if (d < (unsigned)nNodes) atomicAdd(&deg[d], 1);
    }
}

// ---------------- scan stage 1 ----------------
__global__ void k_scan1(const int* __restrict__ deg, int* __restrict__ off,
                        int* __restrict__ bs, int nNodes) {
    __shared__ int tmp[256];
    int t = threadIdx.x;
    int i = blockIdx.x * 256 + t;
    int v = (i < nNodes) ? deg[i] : 0;
    tmp[t] = v;
    __syncthreads();
    for (int d = 1; d < 256; d <<= 1) {
        int add = (t >= d) ? tmp[t - d] : 0;
        __syncthreads();
        tmp[t] += add;
        __syncthreads();
    }
    if (i < nNodes) off[i] = tmp[t] - v;
    if (t == 255) bs[blockIdx.x] = tmp[255];
}

// ---------------- scan stage 2 (1 block) ----------------
__global__ void k_scan2(int* __restrict__ bs, int nb) {
    __shared__ int tmp[512];
    int t = threadIdx.x;
    int carry = 0;
    for (int start = 0; start < nb; start += 512) {
        int i = start + t;
        int v = (i < nb) ? bs[i] : 0;
        tmp[t] = v;
        __syncthreads();
        for (int d = 1; d < 512; d <<= 1) {
            int add = (t >= d) ? tmp[t - d] : 0;
            __syncthreads();
            tmp[t] += add;
            __syncthreads();
        }
        int incl = tmp[t];
        if (i < nb) bs[i] = incl - v + carry;
        int total = tmp[511];
        __syncthreads();
        carry += total;
    }
}

// ---------------- scan stage 3 ----------------
__global__ void k_scan3(int* __restrict__ off, const int* __restrict__ bs, int nNodes) {
    int i = blockIdx.x * 256 + threadIdx.x;
    if (i < nNodes) off[i] += bs[blockIdx.x];
}

// ---------------- CSR fill ----------------
__global__ void k_fill(const int* __restrict__ src, const int* __restrict__ dst,
                       const int* __restrict__ off, int* __restrict__ cur,
                       int* __restrict__ adj, int E, int nNodes) {
    int i = blockIdx.x * blockDim.x + threadIdx.x;
    if (i < E) {
        unsigned d = (unsigned)dst[i];
        unsigned s = (unsigned)src[i];
        if (d < (unsigned)nNodes && s < (unsigned)nNodes) {
            int pos = atomicAdd(&cur[d], 1);
            adj[off[d] + pos] = (int)s;
        }
    }
}

// ---------------- gather-mean helper (R5 verbatim, pitch-templated) ----------------
template <int PITCH>
__device__ __forceinline__ void gather_rows(const float* __restrict__ feat,
                                            const int* __restrict__ adj,
                                            const int* __restrict__ off,
                                            const int* __restrict__ deg,
                                            float (*ms)[PITCH],
                                            int base, int nNodes, int tid) {
    int w = tid >> 6, lane = tid & 63;
    int half = lane >> 5, l32 = lane & 31;
    const float4* feat4 = (const float4*)feat;
    for (int r = w * 8; r < w * 8 + 8; ++r) {
        int n = base + r;
        float4 a = make_float4(0.f, 0.f, 0.f, 0.f);
        float inv = 1.f;
        if (n < nNodes) {
            int o0 = off[n];
            int dg = deg[n];
            int o1 = o0 + dg;
            int k = o0 + half;
            for (; k + 6 < o1; k += 8) {
                int s0 = adj[k + 0];
                int s1 = adj[k + 2];
                int s2 = adj[k + 4];
                int s3 = adj[k + 6];
                float4 v0 = feat4[(long long)s0 * 32 + l32];
                float4 v1 = feat4[(long long)s1 * 32 + l32];
                float4 v2 = feat4[(long long)s2 * 32 + l32];
                float4 v3 = feat4[(long long)s3 * 32 + l32];
                a.x += v0.x + v1.x + v2.x + v3.x;
                a.y += v0.y + v1.y + v2.y + v3.y;
                a.z += v0.z + v1.z + v2.z + v3.z;
                a.w += v0.w + v1.w + v2.w + v3.w;
            }
            for (; k < o1; k += 2) {
                int s = adj[k];
                float4 v = feat4[(long long)s * 32 + l32];
                a.x += v.x; a.y += v.y; a.z += v.z; a.w += v.w;
            }
            inv = 1.f / fmaxf((float)dg, 1.f);
        }
        a.x += __shfl_xor(a.x, 32);
        a.y += __shfl_xor(a.y, 32);
        a.z += __shfl_xor(a.z, 32);
        a.w += __shfl_xor(a.w, 32);
        if (half == 0) {
            a.x *= inv; a.y *= inv; a.z *= inv; a.w *= inv;
            ((float4*)&ms[r][0])[l32] = a;
        }
    }
}

// per-j FMA step macro: J = k within granule, COMP = float4 component
#define SAGE_STEP(J, COMP, NCH, WR4, WL4, RSTRIDE)                        \
    {                                                                     \
        float4 wr4 = WR4[(kc * 4 + J) * RSTRIDE + cg];                    \
        float4 wl4 = WL4[(kc * 4 + J) * RSTRIDE + cg];                    \
        _Pragma("unroll")                                                 \
        for (int rr = 0; rr < NROWS; ++rr) {                              \
            float xvj = xv[rr].COMP, mvj = mv[rr].COMP;                   \
            acc[rr][0] += xvj * wr4.x + mvj * wl4.x;                      \
            acc[rr][1] += xvj * wr4.y + mvj * wl4.y;                      \
            acc[rr][2] += xvj * wr4.z + mvj * wl4.z;                      \
            acc[rr][3] += xvj * wr4.w + mvj * wl4.w;                      \
        }                                                                 \
    }

// ---------------- fused gather + SAGE layer 1 ----------------
// 32 nodes/block, 256 threads. Dense: cg = tid&31 -> ch 4cg..4cg+3,
// rg = tid>>5 -> rows rg*4..+3. Weights read from transposed Wt (coalesced).
__launch_bounds__(256)
__global__ void k_sage1(const float* __restrict__ x,
                        const int* __restrict__ adj, const int* __restrict__ off,
                        const int* __restrict__ deg,
                        const float* __restrict__ Wtl, const float* __restrict__ bl,
                        const float* __restrict__ Wtr,
                        float* __restrict__ h, int nNodes) {
    __shared__ float xs[32][128];
    __shared__ float ms[32][128];
    int tid = threadIdx.x;
    int base = blockIdx.x * 32;

    for (int i = tid; i < 32 * 32; i += 256) {
        int row = i >> 5, col4 = i & 31;
        int n = base + row;
        float4 xv = make_float4(0.f, 0.f, 0.f, 0.f);
        if (n < nNodes) xv = ((const float4*)x)[(long long)n * 32 + col4];
        ((float4*)&xs[row][0])[col4] = xv;
    }

    gather_rows<128>(x, adj, off, deg, ms, base, nNodes, tid);
    __syncthreads();

    const int NROWS = 4;
    int cg = tid & 31;
    int rg = tid >> 5;
    float acc[4][4];
#pragma unroll
    for (int rr = 0; rr < 4; ++rr)
#pragma unroll
        for (int cc = 0; cc < 4; ++cc) acc[rr][cc] = 0.f;

    const float4* WtR4 = (const float4*)Wtr;
    const float4* WtL4 = (const float4*)Wtl;

    for (int kc = 0; kc < 32; ++kc) {
        float4 xv[4], mv[4];
#pragma unroll
        for (int rr = 0; rr < 4; ++rr) {
            xv[rr] = ((const float4*)&xs[rg * 4 + rr][0])[kc];
            mv[rr] = ((const float4*)&ms[rg * 4 + rr][0])[kc];
        }
        SAGE_STEP(0, x, 4, WtR4, WtL4, 32)
        SAGE_STEP(1, y, 4, WtR4, WtL4, 32)
        SAGE_STEP(2, z, 4, WtR4, WtL4, 32)
        SAGE_STEP(3, w, 4, WtR4, WtL4, 32)
    }

    float4 b4 = ((const float4*)bl)[cg];
#pragma unroll
    for (int rr = 0; rr < 4; ++rr) {
        int n = base + rg * 4 + rr;
        if (n < nNodes) {
            float4 o;
            o.x = fmaxf(acc[rr][0] + b4.x, 0.f);
            o.y = fmaxf(acc[rr][1] + b4.y, 0.f);
            o.z = fmaxf(acc[rr][2] + b4.z, 0.f);
            o.w = fmaxf(acc[rr][3] + b4.w, 0.f);
            ((float4*)h)[(long long)n * 32 + cg] = o;
        }
    }
}

// ---------------- fused gather + SAGE layer 2 (64 out ch, no relu) ----------------
// cg = tid&15 -> ch 4cg..4cg+3 (of 64); rg = tid>>4 -> rows rg*2..+1.
// LDS rows padded to 132 floats to break the 4-row bank aliasing.
__launch_bounds__(256)
__global__ void k_sage2(const float* __restrict__ hin,
                        const int* __restrict__ adj, const int* __restrict__ off,
                        const int* __restrict__ deg,
                        const float* __restrict__ Wtl, const float* __restrict__ bl,
                        const float* __restrict__ Wtr,
                        float* __restrict__ z, int nNodes) {
    __shared__ float xs[32][132];
    __shared__ float ms[32][132];
    int tid = threadIdx.x;
    int base = blockIdx.x * 32;

    for (int i = tid; i < 32 * 32; i += 256) {
        int row = i >> 5, col4 = i & 31;
        int n = base + row;
        float4 xv = make_float4(0.f, 0.f, 0.f, 0.f);
        if (n < nNodes) xv = ((const float4*)hin)[(long long)n * 32 + col4];
        ((float4*)&xs[row][0])[col4] = xv;
    }

    gather_rows<132>(hin, adj, off, deg, ms, base, nNodes, tid);
    __syncthreads();

    const int NROWS = 2;
    int cg = tid & 15;
    int rg = tid >> 4;
    float acc[2][4];
#pragma unroll
    for (int rr = 0; rr < 2; ++rr)
#pragma unroll
        for (int cc = 0; cc < 4; ++cc) acc[rr][cc] = 0.f;

    const float4* WtR4 = (const float4*)Wtr;
    const float4* WtL4 = (const float4*)Wtl;

    for (int kc = 0; kc < 32; ++kc) {
        float4 xv[2], mv[2];
#pragma unroll
        for (int rr = 0; rr < 2; ++rr) {
            xv[rr] = ((const float4*)&xs[rg * 2 + rr][0])[kc];
            mv[rr] = ((const float4*)&ms[rg * 2 + rr][0])[kc];
        }
        SAGE_STEP(0, x, 2, WtR4, WtL4, 16)
        SAGE_STEP(1, y, 2, WtR4, WtL4, 16)
        SAGE_STEP(2, z, 2, WtR4, WtL4, 16)
        SAGE_STEP(3, w, 2, WtR4, WtL4, 16)
    }

    float4 b4 = ((const float4*)bl)[cg];
#pragma unroll
    for (int rr = 0; rr < 2; ++rr) {
        int n = base + rg * 2 + rr;
        if (n < nNodes) {
            float4 o;
            o.x = acc[rr][0] + b4.x;
            o.y = acc[rr][1] + b4.y;
            o.z = acc[rr][2] + b4.z;
            o.w = acc[rr][3] + b4.w;
            ((float4*)z)[(long long)n * 16 + cg] = o;
        }
    }
}

// ---------------- decoder: out = z @ W_dec^T + b_dec (transposed weights) ----------------
// cg = tid&31 -> ch 4cg..+3; rg = tid>>5 -> rows rg*4..+3; K=64 (16 granules).
__launch_bounds__(256)
__global__ void k_dec(const float* __restrict__ z, const float* __restrict__ Wt,
                      const float* __restrict__ b,
                      float* __restrict__ out, int nNodes) {
    __shared__ float zs[32][64];
    int tid = threadIdx.x;
    int base = blockIdx.x * 32;

    for (int i = tid; i < 32 * 16; i += 256) {
        int row = i >> 4, col4 = i & 15;
        int n = base + row;
        float4 zv = make_float4(0.f, 0.f, 0.f, 0.f);
        if (n < nNodes) zv = ((const float4*)z)[(long long)n * 16 + col4];
        ((float4*)&zs[row][0])[col4] = zv;
    }
    __syncthreads();

    int cg = tid & 31;
    int rg = tid >> 5;
    float acc[4][4];
#pragma unroll
    for (int rr = 0; rr < 4; ++rr)
#pragma unroll
        for (int cc = 0; cc < 4; ++cc) acc[rr][cc] = 0.f;

    const float4* Wt4 = (const float4*)Wt;

    for (int kc = 0; kc < 16; ++kc) {
        float4 zv[4];
#pragma unroll
        for (int rr = 0; rr < 4; ++rr)
            zv[rr] = ((const float4*)&zs[rg * 4 + rr][0])[kc];
#define DEC_STEP(J, COMP)                                                  \
        {                                                                  \
            float4 w4 = Wt4[(kc * 4 + J) * 32 + cg];                       \
            _Pragma("unroll")                                              \
            for (int rr = 0; rr < 4; ++rr) {                               \
                float zj = zv[rr].COMP;                                    \
                acc[rr][0] += zj * w4.x;                                   \
                acc[rr][1] += zj * w4.y;                                   \
                acc[rr][2] += zj * w4.z;                                   \
                acc[rr][3] += zj * w4.w;                                   \
            }                                                              \
        }
        DEC_STEP(0, x)
        DEC_STEP(1, y)
        DEC_STEP(2, z)
        DEC_STEP(3, w)
#undef DEC_STEP
    }

    float4 b4 = ((const float4*)b)[cg];
#pragma unroll
    for (int rr = 0; rr < 4; ++rr) {
        int n = base + rg * 4 + rr;
        if (n < nNodes) {
            float4 o;
            o.x = acc[rr][0] + b4.x;
            o.y = acc[rr][1] + b4.y;
            o.z = acc[rr][2] + b4.z;
            o.w = acc[rr][3] + b4.w;
            ((float4*)out)[(long long)n * 32 + cg] = o;
        }
    }
}

extern "C" void kernel_launch(void* const* d_in, const int* in_sizes, int n_in,
                              void* d_out, int out_size, void* d_ws, size_t ws_size,
                              hipStream_t stream) {
    const float* x    = (const float*)d_in[0];
    const int*   ei   = (const int*)d_in[1];   // int32 on device
    const float* W1l  = (const float*)d_in[2];
    const float* b1l  = (const float*)d_in[3];
    const float* W1r  = (const float*)d_in[4];
    const float* W2l  = (const float*)d_in[5];
    const float* b2l  = (const float*)d_in[6];
    const float* W2r  = (const float*)d_in[7];
    const float* Wdec = (const float*)d_in[8];
    const float* bdec = (const float*)d_in[9];

    const int N = in_sizes[0] / 128;
    const int E = in_sizes[1] / 2;
    const int nb = (N + 255) / 256;

    const int* src = ei;
    const int* dst = ei + E;

    // ws layout: [float Wt area: wt1l 16384 | wt1r 16384 | wt2l 8192 | wt2r 8192 | wtdec 8192]
    //            [int: adj E | deg N | cur N | off N | bs nb]
    float* wsf   = (float*)d_ws;
    float* wt1l  = wsf;
    float* wt1r  = wt1l + 16384;
    float* wt2l  = wt1r + 16384;
    float* wt2r  = wt2l + 8192;
    float* wtdec = wt2r + 8192;
    int*   adj   = (int*)(wtdec + 8192);
    int*   deg   = adj + E;
    int*   cur   = deg + N;
    int*   off   = cur + N;
    int*   bs    = off + N;

    // weight transposes (tiny)
    k_tw<<<(16384 + 255) / 256, 256, 0, stream>>>(W1l, wt1l, 128, 128);
    k_tw<<<(16384 + 255) / 256, 256, 0, stream>>>(W1r, wt1r, 128, 128);
    k_tw<<<(8192 + 255) / 256, 256, 0, stream>>>(W2l, wt2l, 128, 64);
    k_tw<<<(8192 + 255) / 256, 256, 0, stream>>>(W2r, wt2r, 128, 64);
    k_tw<<<(8192 + 255) / 256, 256, 0, stream>>>(Wdec, wtdec, 64, 128);

    hipMemsetAsync(deg, 0, (size_t)2 * N * sizeof(int), stream);

    k_deg  <<<(E + 255) / 256, 256, 0, stream>>>(dst, deg, E, N);
    k_scan1<<<nb, 256, 0, stream>>>(deg, off, bs, N);
    k_scan2<<<1, 512, 0, stream>>>(bs, nb);
    k_scan3<<<nb, 256, 0, stream>>>(off, bs, N);
    k_fill <<<(E + 255) / 256, 256, 0, stream>>>(src, dst, off, cur, adj, E, N);

    // d_out layout: x_recon [N*128] then z [N*64]; park h in x_recon region
    float* outp = (float*)d_out;
    float* h    = outp;
    float* z    = outp + (long long)N * 128;
    float* xrec = outp;

    const int nblk = (N + 31) / 32;
    k_sage1<<<nblk, 256, 0, stream>>>(x, adj, off, deg, wt1l, b1l, wt1r, h, N);
    k_sage2<<<nblk, 256, 0, stream>>>(h, adj, off, deg, wt2l, b2l, wt2r, z, N);
    k_dec  <<<nblk, 256, 0, stream>>>(z, wtdec, bdec, xrec, N);
}

// Round 9
// 638.774 us; speedup vs baseline: 1.8935x; 1.0364x over previous
//
#include <hip/hip_runtime.h>

// N = 100000 nodes, E = 1600000 edges, IN=128, HID=128, LAT=64
// edge_index arrives on device as int32 (harness converts integer inputs).
//
// R8 structure + bf16 gather path: features gathered as bf16 (halves the
// L2-miss traffic that bounds the gather). x converted once to bf16; sage1
// writes h as bf16 (RNE); dense math, weights, outputs stay f32.
// bf16 tensors live in the x_recon region of d_out (decoder overwrites last).

__device__ __forceinline__ unsigned short f2b(float f) {
    unsigned u = __float_as_uint(f);
    unsigned r = (u + 0x7fffu + ((u >> 16) & 1u)) >> 16;   // RNE
    return (unsigned short)r;
}
#define U2F_LO(u) __uint_as_float((u) << 16)
#define U2F_HI(u) __uint_as_float((u) & 0xffff0000u)

// ---------------- f32 -> bf16 convert (vectorized x4) ----------------
__global__ void k_cvt(const float* __restrict__ in, ushort* __restrict__ ob, int n4) {
    int i = blockIdx.x * blockDim.x + threadIdx.x;
    if (i < n4) {
        float4 v = ((const float4*)in)[i];
        ushort4 o;
        o.x = f2b(v.x); o.y = f2b(v.y); o.z = f2b(v.z); o.w = f2b(v.w);
        ((ushort4*)ob)[i] = o;
    }
}

// ---------------- weight transpose: Wt[k][c] = W[c][k] ----------------
__global__ void k_tw(const float* __restrict__ W, float* __restrict__ Wt, int K, int OC) {
    int i = blockIdx.x * blockDim.x + threadIdx.x;
    if (i < K * OC) {
        int k = i / OC, c = i % OC;
        Wt[i] = W[c * K + k];
    }
}

// ---------------- degree (int): deg[dst]++ ----------------
__global__ void k_deg(const int* __restrict__ dst, int* __restrict__ deg, int E, int nNodes) {
    int i = blockIdx.x * blockDim.x + threadIdx.x;
    if (i < E) {
        unsigned d = (unsigned)dst[i];
        if (d < (unsigned)nNodes) atomicAdd(&deg[d], 1);
    }
}

// ---------------- scan stage 1 ----------------
__global__ void k_scan1(const int* __restrict__ deg, int* __restrict__ off,
                        int* __restrict__ bs, int nNodes) {
    __shared__ int tmp[256];
    int t = threadIdx.x;
    int i = blockIdx.x * 256 + t;
    int v = (i < nNodes) ? deg[i] : 0;
    tmp[t] = v;
    __syncthreads();
    for (int d = 1; d < 256; d <<= 1) {
        int add = (t >= d) ? tmp[t - d] : 0;
        __syncthreads();
        tmp[t] += add;
        __syncthreads();
    }
    if (i < nNodes) off[i] = tmp[t] - v;
    if (t == 255) bs[blockIdx.x] = tmp[255];
}

// ---------------- scan stage 2 (1 block) ----------------
__global__ void k_scan2(int* __restrict__ bs, int nb) {
    __shared__ int tmp[512];
    int t = threadIdx.x;
    int carry = 0;
    for (int start = 0; start < nb; start += 512) {
        int i = start + t;
        int v = (i < nb) ? bs[i] : 0;
        tmp[t] = v;
        __syncthreads();
        for (int d = 1; d < 512; d <<= 1) {
            int add = (t >= d) ? tmp[t - d] : 0;
            __syncthreads();
            tmp[t] += add;
            __syncthreads();
        }
        int incl = tmp[t];
        if (i < nb) bs[i] = incl - v + carry;
        int total = tmp[511];
        __syncthreads();
        carry += total;
    }
}

// ---------------- scan stage 3 ----------------
__global__ void k_scan3(int* __restrict__ off, const int* __restrict__ bs, int nNodes) {
    int i = blockIdx.x * 256 + threadIdx.x;
    if (i < nNodes) off[i] += bs[blockIdx.x];
}

// ---------------- CSR fill ----------------
__global__ void k_fill(const int* __restrict__ src, const int* __restrict__ dst,
                       const int* __restrict__ off, int* __restrict__ cur,
                       int* __restrict__ adj, int E, int nNodes) {
    int i = blockIdx.x * blockDim.x + threadIdx.x;
    if (i < E) {
        unsigned d = (unsigned)dst[i];
        unsigned s = (unsigned)src[i];
        if (d < (unsigned)nNodes && s < (unsigned)nNodes) {
            int pos = atomicAdd(&cur[d], 1);
            adj[off[d] + pos] = (int)s;
        }
    }
}

// ---------------- bf16 gather-mean (R5 loop structure, uint2 = 4 bf16/lane) ----------------
template <int PITCH>
__device__ __forceinline__ void gather_rows_b(const ushort* __restrict__ feat,
                                              const int* __restrict__ adj,
                                              const int* __restrict__ off,
                                              const int* __restrict__ deg,
                                              float (*ms)[PITCH],
                                              int base, int nNodes, int tid) {
    int w = tid >> 6, lane = tid & 63;
    int half = lane >> 5, l32 = lane & 31;
    const uint2* feat2 = (const uint2*)feat;
    for (int r = w * 8; r < w * 8 + 8; ++r) {
        int n = base + r;
        float4 a = make_float4(0.f, 0.f, 0.f, 0.f);
        float inv = 1.f;
        if (n < nNodes) {
            int o0 = off[n];
            int dg = deg[n];
            int o1 = o0 + dg;
            int k = o0 + half;
            for (; k + 6 < o1; k += 8) {         // 4 neighbors per half in flight
                uint2 v0 = feat2[(long long)adj[k + 0] * 32 + l32];
                uint2 v1 = feat2[(long long)adj[k + 2] * 32 + l32];
                uint2 v2 = feat2[(long long)adj[k + 4] * 32 + l32];
                uint2 v3 = feat2[(long long)adj[k + 6] * 32 + l32];
                a.x += U2F_LO(v0.x) + U2F_LO(v1.x) + U2F_LO(v2.x) + U2F_LO(v3.x);
                a.y += U2F_HI(v0.x) + U2F_HI(v1.x) + U2F_HI(v2.x) + U2F_HI(v3.x);
                a.z += U2F_LO(v0.y) + U2F_LO(v1.y) + U2F_LO(v2.y) + U2F_LO(v3.y);
                a.w += U2F_HI(v0.y) + U2F_HI(v1.y) + U2F_HI(v2.y) + U2F_HI(v3.y);
            }
            for (; k < o1; k += 2) {
                uint2 v = feat2[(long long)adj[k] * 32 + l32];
                a.x += U2F_LO(v.x); a.y += U2F_HI(v.x);
                a.z += U2F_LO(v.y); a.w += U2F_HI(v.y);
            }
            inv = 1.f / fmaxf((float)dg, 1.f);
        }
        a.x += __shfl_xor(a.x, 32);
        a.y += __shfl_xor(a.y, 32);
        a.z += __shfl_xor(a.z, 32);
        a.w += __shfl_xor(a.w, 32);
        if (half == 0) {
            a.x *= inv; a.y *= inv; a.z *= inv; a.w *= inv;
            ((float4*)&ms[r][0])[l32] = a;
        }
    }
}

// per-j FMA step macro: J = k within granule, COMP = float4 component
#define SAGE_STEP(J, COMP, WR4, WL4, RSTRIDE)                             \
    {                                                                     \
        float4 wr4 = WR4[(kc * 4 + J) * RSTRIDE + cg];                    \
        float4 wl4 = WL4[(kc * 4 + J) * RSTRIDE + cg];                    \
        _Pragma("unroll")                                                 \
        for (int rr = 0; rr < NROWS; ++rr) {                              \
            float xvj = xv[rr].COMP, mvj = mv[rr].COMP;                   \
            acc[rr][0] += xvj * wr4.x + mvj * wl4.x;                      \
            acc[rr][1] += xvj * wr4.y + mvj * wl4.y;                      \
            acc[rr][2] += xvj * wr4.z + mvj * wl4.z;                      \
            acc[rr][3] += xvj * wr4.w + mvj * wl4.w;                      \
        }                                                                 \
    }

// ---------------- fused gather + SAGE layer 1 ----------------
// xs from f32 x (self term, better precision); gather from bf16 xh.
// Output h written as bf16 (hb). 32 nodes/block, 256 threads.
__launch_bounds__(256)
__global__ void k_sage1(const float* __restrict__ x, const ushort* __restrict__ xh,
                        const int* __restrict__ adj, const int* __restrict__ off,
                        const int* __restrict__ deg,
                        const float* __restrict__ Wtl, const float* __restrict__ bl,
                        const float* __restrict__ Wtr,
                        ushort* __restrict__ hb, int nNodes) {
    __shared__ float xs[32][128];
    __shared__ float ms[32][128];
    int tid = threadIdx.x;
    int base = blockIdx.x * 32;

    for (int i = tid; i < 32 * 32; i += 256) {
        int row = i >> 5, col4 = i & 31;
        int n = base + row;
        float4 xv = make_float4(0.f, 0.f, 0.f, 0.f);
        if (n < nNodes) xv = ((const float4*)x)[(long long)n * 32 + col4];
        ((float4*)&xs[row][0])[col4] = xv;
    }

    gather_rows_b<128>(xh, adj, off, deg, ms, base, nNodes, tid);
    __syncthreads();

    const int NROWS = 4;
    int cg = tid & 31;
    int rg = tid >> 5;
    float acc[4][4];
#pragma unroll
    for (int rr = 0; rr < 4; ++rr)
#pragma unroll
        for (int cc = 0; cc < 4; ++cc) acc[rr][cc] = 0.f;

    const float4* WtR4 = (const float4*)Wtr;
    const float4* WtL4 = (const float4*)Wtl;

    for (int kc = 0; kc < 32; ++kc) {
        float4 xv[4], mv[4];
#pragma unroll
        for (int rr = 0; rr < 4; ++rr) {
            xv[rr] = ((const float4*)&xs[rg * 4 + rr][0])[kc];
            mv[rr] = ((const float4*)&ms[rg * 4 + rr][0])[kc];
        }
        SAGE_STEP(0, x, WtR4, WtL4, 32)
        SAGE_STEP(1, y, WtR4, WtL4, 32)
        SAGE_STEP(2, z, WtR4, WtL4, 32)
        SAGE_STEP(3, w, WtR4, WtL4, 32)
    }

    float4 b4 = ((const float4*)bl)[cg];
#pragma unroll
    for (int rr = 0; rr < 4; ++rr) {
        int n = base + rg * 4 + rr;
        if (n < nNodes) {
            ushort4 o;
            o.x = f2b(fmaxf(acc[rr][0] + b4.x, 0.f));
            o.y = f2b(fmaxf(acc[rr][1] + b4.y, 0.f));
            o.z = f2b(fmaxf(acc[rr][2] + b4.z, 0.f));
            o.w = f2b(fmaxf(acc[rr][3] + b4.w, 0.f));
            ((ushort4*)hb)[(long long)n * 32 + cg] = o;
        }
    }
}

// ---------------- fused gather + SAGE layer 2 (64 out ch, no relu) ----------------
// Self tile AND gather both from bf16 hb; z written f32. LDS rows padded to 132.
__launch_bounds__(256)
__global__ void k_sage2(const ushort* __restrict__ hb,
                        const int* __restrict__ adj, const int* __restrict__ off,
                        const int* __restrict__ deg,
                        const float* __restrict__ Wtl, const float* __restrict__ bl,
                        const float* __restrict__ Wtr,
                        float* __restrict__ z, int nNodes) {
    __shared__ float xs[32][132];
    __shared__ float ms[32][132];
    int tid = threadIdx.x;
    int base = blockIdx.x * 32;

    for (int i = tid; i < 32 * 32; i += 256) {
        int row = i >> 5, col4 = i & 31;
        int n = base + row;
        float4 xv = make_float4(0.f, 0.f, 0.f, 0.f);
        if (n < nNodes) {
            uint2 v = ((const uint2*)hb)[(long long)n * 32 + col4];
            xv.x = U2F_LO(v.x); xv.y = U2F_HI(v.x);
            xv.z = U2F_LO(v.y); xv.w = U2F_HI(v.y);
        }
        ((float4*)&xs[row][0])[col4] = xv;
    }

    gather_rows_b<132>(hb, adj, off, deg, ms, base, nNodes, tid);
    __syncthreads();

    const int NROWS = 2;
    int cg = tid & 15;
    int rg = tid >> 4;
    float acc[2][4];
#pragma unroll
    for (int rr = 0; rr < 2; ++rr)
#pragma unroll
        for (int cc = 0; cc < 4; ++cc) acc[rr][cc] = 0.f;

    const float4* WtR4 = (const float4*)Wtr;
    const float4* WtL4 = (const float4*)Wtl;

    for (int kc = 0; kc < 32; ++kc) {
        float4 xv[2], mv[2];
#pragma unroll
        for (int rr = 0; rr < 2; ++rr) {
            xv[rr] = ((const float4*)&xs[rg * 2 + rr][0])[kc];
            mv[rr] = ((const float4*)&ms[rg * 2 + rr][0])[kc];
        }
        SAGE_STEP(0, x, WtR4, WtL4, 16)
        SAGE_STEP(1, y, WtR4, WtL4, 16)
        SAGE_STEP(2, z, WtR4, WtL4, 16)
        SAGE_STEP(3, w, WtR4, WtL4, 16)
    }

    float4 b4 = ((const float4*)bl)[cg];
#pragma unroll
    for (int rr = 0; rr < 2; ++rr) {
        int n = base + rg * 2 + rr;
        if (n < nNodes) {
            float4 o;
            o.x = acc[rr][0] + b4.x;
            o.y = acc[rr][1] + b4.y;
            o.z = acc[rr][2] + b4.z;
            o.w = acc[rr][3] + b4.w;
            ((float4*)z)[(long long)n * 16 + cg] = o;
        }
    }
}

// ---------------- decoder: out = z @ W_dec^T + b_dec (R8 verbatim) ----------------
__launch_bounds__(256)
__global__ void k_dec(const float* __restrict__ z, const float* __restrict__ Wt,
                      const float* __restrict__ b,
                      float* __restrict__ out, int nNodes) {
    __shared__ float zs[32][64];
    int tid = threadIdx.x;
    int base = blockIdx.x * 32;

    for (int i = tid; i < 32 * 16; i += 256) {
        int row = i >> 4, col4 = i & 15;
        int n = base + row;
        float4 zv = make_float4(0.f, 0.f, 0.f, 0.f);
        if (n < nNodes) zv = ((const float4*)z)[(long long)n * 16 + col4];
        ((float4*)&zs[row][0])[col4] = zv;
    }
    __syncthreads();

    int cg = tid & 31;
    int rg = tid >> 5;
    float acc[4][4];
#pragma unroll
    for (int rr = 0; rr < 4; ++rr)
#pragma unroll
        for (int cc = 0; cc < 4; ++cc) acc[rr][cc] = 0.f;

    const float4* Wt4 = (const float4*)Wt;

    for (int kc = 0; kc < 16; ++kc) {
        float4 zv[4];
#pragma unroll
        for (int rr = 0; rr < 4; ++rr)
            zv[rr] = ((const float4*)&zs[rg * 4 + rr][0])[kc];
#define DEC_STEP(J, COMP)                                                  \
        {                                                                  \
            float4 w4 = Wt4[(kc * 4 + J) * 32 + cg];                       \
            _Pragma("unroll")                                              \
            for (int rr = 0; rr < 4; ++rr) {                               \
                float zj = zv[rr].COMP;                                    \
                acc[rr][0] += zj * w4.x;                                   \
                acc[rr][1] += zj * w4.y;                                   \
                acc[rr][2] += zj * w4.z;                                   \
                acc[rr][3] += zj * w4.w;                                   \
            }                                                              \
        }
        DEC_STEP(0, x)
        DEC_STEP(1, y)
        DEC_STEP(2, z)
        DEC_STEP(3, w)
#undef DEC_STEP
    }

    float4 b4 = ((const float4*)b)[cg];
#pragma unroll
    for (int rr = 0; rr < 4; ++rr) {
        int n = base + rg * 4 + rr;
        if (n < nNodes) {
            float4 o;
            o.x = acc[rr][0] + b4.x;
            o.y = acc[rr][1] + b4.y;
            o.z = acc[rr][2] + b4.z;
            o.w = acc[rr][3] + b4.w;
            ((float4*)out)[(long long)n * 32 + cg] = o;
        }
    }
}

extern "C" void kernel_launch(void* const* d_in, const int* in_sizes, int n_in,
                              void* d_out, int out_size, void* d_ws, size_t ws_size,
                              hipStream_t stream) {
    const float* x    = (const float*)d_in[0];
    const int*   ei   = (const int*)d_in[1];   // int32 on device
    const float* W1l  = (const float*)d_in[2];
    const float* b1l  = (const float*)d_in[3];
    const float* W1r  = (const float*)d_in[4];
    const float* W2l  = (const float*)d_in[5];
    const float* b2l  = (const float*)d_in[6];
    const float* W2r  = (const float*)d_in[7];
    const float* Wdec = (const float*)d_in[8];
    const float* bdec = (const float*)d_in[9];

    const int N = in_sizes[0] / 128;
    const int E = in_sizes[1] / 2;
    const int nb = (N + 255) / 256;

    const int* src = ei;
    const int* dst = ei + E;

    // ws: [float Wt: wt1l 16384 | wt1r 16384 | wt2l 8192 | wt2r 8192 | wtdec 8192]
    //     [int: adj E | deg N | cur N | off N | bs nb]
    float* wsf   = (float*)d_ws;
    float* wt1l  = wsf;
    float* wt1r  = wt1l + 16384;
    float* wt2l  = wt1r + 16384;
    float* wt2r  = wt2l + 8192;
    float* wtdec = wt2r + 8192;
    int*   adj   = (int*)(wtdec + 8192);
    int*   deg   = adj + E;
    int*   cur   = deg + N;
    int*   off   = cur + N;
    int*   bs    = off + N;

    // d_out layout: x_recon [N*128 f32] then z [N*64 f32].
    // Park bf16 tensors inside the x_recon region (overwritten by k_dec last):
    //   xh = bf16(x)  : first N*64 floats' worth
    //   hb = bf16(h)  : next  N*64 floats' worth
    float*  outp = (float*)d_out;
    float*  z    = outp + (long long)N * 128;
    float*  xrec = outp;
    ushort* xh   = (ushort*)outp;
    ushort* hb   = (ushort*)(outp + (long long)N * 64);

    // weight transposes + x->bf16 (tiny)
    k_tw<<<(16384 + 255) / 256, 256, 0, stream>>>(W1l, wt1l, 128, 128);
    k_tw<<<(16384 + 255) / 256, 256, 0, stream>>>(W1r, wt1r, 128, 128);
    k_tw<<<(8192 + 255) / 256, 256, 0, stream>>>(W2l, wt2l, 128, 64);
    k_tw<<<(8192 + 255) / 256, 256, 0, stream>>>(W2r, wt2r, 128, 64);
    k_tw<<<(8192 + 255) / 256, 256, 0, stream>>>(Wdec, wtdec, 64, 128);
    k_cvt<<<(N * 32 + 255) / 256, 256, 0, stream>>>(x, xh, N * 32);

    hipMemsetAsync(deg, 0, (size_t)2 * N * sizeof(int), stream);

    k_deg  <<<(E + 255) / 256, 256, 0, stream>>>(dst, deg, E, N);
    k_scan1<<<nb, 256, 0, stream>>>(deg, off, bs, N);
    k_scan2<<<1, 512, 0, stream>>>(bs, nb);
    k_scan3<<<nb, 256, 0, stream>>>(off, bs, N);
    k_fill <<<(E + 255) / 256, 256, 0, stream>>>(src, dst, off, cur, adj, E, N);

    const int nblk = (N + 31) / 32;
    k_sage1<<<nblk, 256, 0, stream>>>(x, xh, adj, off, deg, wt1l, b1l, wt1r, hb, N);
    k_sage2<<<nblk, 256, 0, stream>>>(hb, adj, off, deg, wt2l, b2l, wt2r, z, N);
    k_dec  <<<nblk, 256, 0, stream>>>(z, wtdec, bdec, xrec, N);
}

// Round 10
// 593.006 us; speedup vs baseline: 2.0396x; 1.0772x over previous
//
#include <hip/hip_runtime.h>
#include <hip/hip_fp16.h>

// N = 100000 nodes, E = 1600000 edges, IN=128, HID=128, LAT=64
// edge_index arrives on device as int32 (harness converts integer inputs).
//
// R9 structure, gather reworked: fp16 features, packed __hadd2 accumulation
// (4x less gather VALU), uint4 16B/lane loads with 16-lane quarter groups
// (half the VMEM instructions; 16 neighbor rows in flight per wave).

__device__ __forceinline__ unsigned h2u(__half2 h) { union { __half2 h; unsigned u; } c; c.h = h; return c.u; }
__device__ __forceinline__ __half2 u2h(unsigned u) { union { unsigned u; __half2 h; } c; c.u = u; return c.h; }

// ---------------- f32 -> fp16 convert (x4) ----------------
__global__ void k_cvt(const float* __restrict__ in, unsigned* __restrict__ ob, int n4) {
    int i = blockIdx.x * blockDim.x + threadIdx.x;
    if (i < n4) {
        float4 v = ((const float4*)in)[i];
        uint2 o;
        o.x = h2u(__floats2half2_rn(v.x, v.y));
        o.y = h2u(__floats2half2_rn(v.z, v.w));
        ((uint2*)ob)[i] = o;
    }
}

// ---------------- merged weight transposes: Wt[k][c] = W[c][k] ----------------
__global__ void k_tw5(const float* __restrict__ W1l, const float* __restrict__ W1r,
                      const float* __restrict__ W2l, const float* __restrict__ W2r,
                      const float* __restrict__ Wdec,
                      float* __restrict__ wt1l, float* __restrict__ wt1r,
                      float* __restrict__ wt2l, float* __restrict__ wt2r,
                      float* __restrict__ wtdec) {
    int i = blockIdx.x * blockDim.x + threadIdx.x;   // 0 .. 57343
    const float* W; float* Wt; int K, OC, j;
    if (i < 16384)      { W = W1l;  Wt = wt1l;  K = 128; OC = 128; j = i; }
    else if (i < 32768) { W = W1r;  Wt = wt1r;  K = 128; OC = 128; j = i - 16384; }
    else if (i < 40960) { W = W2l;  Wt = wt2l;  K = 128; OC = 64;  j = i - 32768; }
    else if (i < 49152) { W = W2r;  Wt = wt2r;  K = 128; OC = 64;  j = i - 40960; }
    else if (i < 57344) { W = Wdec; Wt = wtdec; K = 64;  OC = 128; j = i - 49152; }
    else return;
    int k = j / OC, c = j % OC;
    Wt[j] = W[c * K + k];
}

// ---------------- degree (int): deg[dst]++ ----------------
__global__ void k_deg(const int* __restrict__ dst, int* __restrict__ deg, int E, int nNodes) {
    int i = blockIdx.x * blockDim.x + threadIdx.x;
    if (i < E) {
        unsigned d = (unsigned)dst[i];
        if (d < (unsigned)nNodes) atomicAdd(&deg[d], 1);
    }
}

// ---------------- scan stage 1 ----------------
__global__ void k_scan1(const int* __restrict__ deg, int* __restrict__ off,
                        int* __restrict__ bs, int nNodes) {
    __shared__ int tmp[256];
    int t = threadIdx.x;
    int i = blockIdx.x * 256 + t;
    int v = (i < nNodes) ? deg[i] : 0;
    tmp[t] = v;
    __syncthreads();
    for (int d = 1; d < 256; d <<= 1) {
        int add = (t >= d) ? tmp[t - d] : 0;
        __syncthreads();
        tmp[t] += add;
        __syncthreads();
    }
    if (i < nNodes) off[i] = tmp[t] - v;
    if (t == 255) bs[blockIdx.x] = tmp[255];
}

// ---------------- scan stage 2 (1 block) ----------------
__global__ void k_scan2(int* __restrict__ bs, int nb) {
    __shared__ int tmp[512];
    int t = threadIdx.x;
    int carry = 0;
    for (int start = 0; start < nb; start += 512) {
        int i = start + t;
        int v = (i < nb) ? bs[i] : 0;
        tmp[t] = v;
        __syncthreads();
        for (int d = 1; d < 512; d <<= 1) {
            int add = (t >= d) ? tmp[t - d] : 0;
            __syncthreads();
            tmp[t] += add;
            __syncthreads();
        }
        int incl = tmp[t];
        if (i < nb) bs[i] = incl - v + carry;
        int total = tmp[511];
        __syncthreads();
        carry += total;
    }
}

// ---------------- scan stage 3 ----------------
__global__ void k_scan3(int* __restrict__ off, const int* __restrict__ bs, int nNodes) {
    int i = blockIdx.x * 256 + threadIdx.x;
    if (i < nNodes) off[i] += bs[blockIdx.x];
}

// ---------------- CSR fill ----------------
__global__ void k_fill(const int* __restrict__ src, const int* __restrict__ dst,
                       const int* __restrict__ off, int* __restrict__ cur,
                       int* __restrict__ adj, int E, int nNodes) {
    int i = blockIdx.x * blockDim.x + threadIdx.x;
    if (i < E) {
        unsigned d = (unsigned)dst[i];
        unsigned s = (unsigned)src[i];
        if (d < (unsigned)nNodes && s < (unsigned)nNodes) {
            int pos = atomicAdd(&cur[d], 1);
            adj[off[d] + pos] = (int)s;
        }
    }
}

// ---------------- fp16 gather-mean ----------------
// Wave w handles rows w*8..w*8+7. Lane split: quarter q = (lane>>4)&3 takes
// neighbors k = o0+q step 4; lane-in-quarter lq = lane&15 holds channels
// 8lq..8lq+7 as one uint4 (4 half2). Full group = 16 neighbor rows in flight.
// Packed __hadd2 accumulate; f32 convert + cross-quarter shfl reduce per row.
template <int PITCH>
__device__ __forceinline__ void gather_rows_h(const unsigned short* __restrict__ feat,
                                              const int* __restrict__ adj,
                                              const int* __restrict__ off,
                                              const int* __restrict__ deg,
                                              float (*ms)[PITCH],
                                              int base, int nNodes, int tid) {
    int w = tid >> 6, lane = tid & 63;
    int q = (lane >> 4) & 3, lq = lane & 15;
    const uint4* feat4 = (const uint4*)feat;   // fp16 row = 16 uint4
    for (int r = w * 8; r < w * 8 + 8; ++r) {
        int n = base + r;
        __half2 acc2[4];
        __half2 zero = __floats2half2_rn(0.f, 0.f);
        acc2[0] = zero; acc2[1] = zero; acc2[2] = zero; acc2[3] = zero;
        float inv = 1.f;
        if (n < nNodes) {
            int o0 = off[n];
            int dg = deg[n];
            int o1 = o0 + dg;
            int kb = o0;
            for (; kb + 15 < o1; kb += 16) {     // full group: 16 neighbors/wave
                int s0 = adj[kb + q];
                int s1 = adj[kb + q + 4];
                int s2 = adj[kb + q + 8];
                int s3 = adj[kb + q + 12];
                uint4 f0 = feat4[(long long)s0 * 16 + lq];
                uint4 f1 = feat4[(long long)s1 * 16 + lq];
                uint4 f2 = feat4[(long long)s2 * 16 + lq];
                uint4 f3 = feat4[(long long)s3 * 16 + lq];
                acc2[0] = __hadd2(acc2[0], __hadd2(__hadd2(u2h(f0.x), u2h(f1.x)),
                                                  __hadd2(u2h(f2.x), u2h(f3.x))));
                acc2[1] = __hadd2(acc2[1], __hadd2(__hadd2(u2h(f0.y), u2h(f1.y)),
                                                  __hadd2(u2h(f2.y), u2h(f3.y))));
                acc2[2] = __hadd2(acc2[2], __hadd2(__hadd2(u2h(f0.z), u2h(f1.z)),
                                                  __hadd2(u2h(f2.z), u2h(f3.z))));
                acc2[3] = __hadd2(acc2[3], __hadd2(__hadd2(u2h(f0.w), u2h(f1.w)),
                                                  __hadd2(u2h(f2.w), u2h(f3.w))));
            }
            for (int k = kb + q; k < o1; k += 4) {   // tail
                uint4 f = feat4[(long long)adj[k] * 16 + lq];
                acc2[0] = __hadd2(acc2[0], u2h(f.x));
                acc2[1] = __hadd2(acc2[1], u2h(f.y));
                acc2[2] = __hadd2(acc2[2], u2h(f.z));
                acc2[3] = __hadd2(acc2[3], u2h(f.w));
            }
            inv = 1.f / fmaxf((float)dg, 1.f);
        }
        float a[8];
#pragma unroll
        for (int j = 0; j < 4; ++j) {
            float2 f = __half22float2(acc2[j]);
            a[2 * j] = f.x; a[2 * j + 1] = f.y;
        }
#pragma unroll
        for (int j = 0; j < 8; ++j) {
            a[j] += __shfl_xor(a[j], 16);
            a[j] += __shfl_xor(a[j], 32);
        }
        if (q == 0 && n < nNodes) {   // lanes 0..15 write the row
            float4 v0 = make_float4(a[0] * inv, a[1] * inv, a[2] * inv, a[3] * inv);
            float4 v1 = make_float4(a[4] * inv, a[5] * inv, a[6] * inv, a[7] * inv);
            ((float4*)&ms[r][0])[lq * 2 + 0] = v0;
            ((float4*)&ms[r][0])[lq * 2 + 1] = v1;
        }
    }
}

// per-j FMA step macro: J = k within granule, COMP = float4 component
#define SAGE_STEP(J, COMP, WR4, WL4, RSTRIDE)                             \
    {                                                                     \
        float4 wr4 = WR4[(kc * 4 + J) * RSTRIDE + cg];                    \
        float4 wl4 = WL4[(kc * 4 + J) * RSTRIDE + cg];                    \
        _Pragma("unroll")                                                 \
        for (int rr = 0; rr < NROWS; ++rr) {                              \
            float xvj = xv[rr].COMP, mvj = mv[rr].COMP;                   \
            acc[rr][0] += xvj * wr4.x + mvj * wl4.x;                      \
            acc[rr][1] += xvj * wr4.y + mvj * wl4.y;                      \
            acc[rr][2] += xvj * wr4.z + mvj * wl4.z;                      \
            acc[rr][3] += xvj * wr4.w + mvj * wl4.w;                      \
        }                                                                 \
    }

// ---------------- fused gather + SAGE layer 1 ----------------
// xs from f32 x (self term); gather from fp16 xh; h written fp16 (hb).
__launch_bounds__(256)
__global__ void k_sage1(const float* __restrict__ x, const unsigned short* __restrict__ xh,
                        const int* __restrict__ adj, const int* __restrict__ off,
                        const int* __restrict__ deg,
                        const float* __restrict__ Wtl, const float* __restrict__ bl,
                        const float* __restrict__ Wtr,
                        unsigned* __restrict__ hb, int nNodes) {
    __shared__ float xs[32][128];
    __shared__ float ms[32][128];
    int tid = threadIdx.x;
    int base = blockIdx.x * 32;

    for (int i = tid; i < 32 * 32; i += 256) {
        int row = i >> 5, col4 = i & 31;
        int n = base + row;
        float4 xv = make_float4(0.f, 0.f, 0.f, 0.f);
        if (n < nNodes) xv = ((const float4*)x)[(long long)n * 32 + col4];
        ((float4*)&xs[row][0])[col4] = xv;
    }

    gather_rows_h<128>(xh, adj, off, deg, ms, base, nNodes, tid);
    __syncthreads();

    const int NROWS = 4;
    int cg = tid & 31;
    int rg = tid >> 5;
    float acc[4][4];
#pragma unroll
    for (int rr = 0; rr < 4; ++rr)
#pragma unroll
        for (int cc = 0; cc < 4; ++cc) acc[rr][cc] = 0.f;

    const float4* WtR4 = (const float4*)Wtr;
    const float4* WtL4 = (const float4*)Wtl;

    for (int kc = 0; kc < 32; ++kc) {
        float4 xv[4], mv[4];
#pragma unroll
        for (int rr = 0; rr < 4; ++rr) {
            xv[rr] = ((const float4*)&xs[rg * 4 + rr][0])[kc];
            mv[rr] = ((const float4*)&ms[rg * 4 + rr][0])[kc];
        }
        SAGE_STEP(0, x, WtR4, WtL4, 32)
        SAGE_STEP(1, y, WtR4, WtL4, 32)
        SAGE_STEP(2, z, WtR4, WtL4, 32)
        SAGE_STEP(3, w, WtR4, WtL4, 32)
    }

    float4 b4 = ((const float4*)bl)[cg];
#pragma unroll
    for (int rr = 0; rr < 4; ++rr) {
        int n = base + rg * 4 + rr;
        if (n < nNodes) {
            float r0 = fmaxf(acc[rr][0] + b4.x, 0.f);
            float r1 = fmaxf(acc[rr][1] + b4.y, 0.f);
            float r2 = fmaxf(acc[rr][2] + b4.z, 0.f);
            float r3 = fmaxf(acc[rr][3] + b4.w, 0.f);
            uint2 st;
            st.x = h2u(__floats2half2_rn(r0, r1));
            st.y = h2u(__floats2half2_rn(r2, r3));
            ((uint2*)hb)[(long long)n * 32 + cg] = st;
        }
    }
}

// ---------------- fused gather + SAGE layer 2 (64 out ch, no relu) ----------------
// Self tile AND gather from fp16 hb; z written f32. LDS rows padded to 132.
__launch_bounds__(256)
__global__ void k_sage2(const unsigned short* __restrict__ hb,
                        const int* __restrict__ adj, const int* __restrict__ off,
                        const int* __restrict__ deg,
                        const float* __restrict__ Wtl, const float* __restrict__ bl,
                        const float* __restrict__ Wtr,
                        float* __restrict__ z, int nNodes) {
    __shared__ float xs[32][132];
    __shared__ float ms[32][132];
    int tid = threadIdx.x;
    int base = blockIdx.x * 32;

    for (int i = tid; i < 32 * 32; i += 256) {
        int row = i >> 5, col4 = i & 31;
        int n = base + row;
        float4 xv = make_float4(0.f, 0.f, 0.f, 0.f);
        if (n < nNodes) {
            uint2 v = ((const uint2*)hb)[(long long)n * 32 + col4];
            float2 f0 = __half22float2(u2h(v.x));
            float2 f1 = __half22float2(u2h(v.y));
            xv = make_float4(f0.x, f0.y, f1.x, f1.y);
        }
        ((float4*)&xs[row][0])[col4] = xv;
    }

    gather_rows_h<132>(hb, adj, off, deg, ms, base, nNodes, tid);
    __syncthreads();

    const int NROWS = 2;
    int cg = tid & 15;
    int rg = tid >> 4;
    float acc[2][4];
#pragma unroll
    for (int rr = 0; rr < 2; ++rr)
#pragma unroll
        for (int cc = 0; cc < 4; ++cc) acc[rr][cc] = 0.f;

    const float4* WtR4 = (const float4*)Wtr;
    const float4* WtL4 = (const float4*)Wtl;

    for (int kc = 0; kc < 32; ++kc) {
        float4 xv[2], mv[2];
#pragma unroll
        for (int rr = 0; rr < 2; ++rr) {
            xv[rr] = ((const float4*)&xs[rg * 2 + rr][0])[kc];
            mv[rr] = ((const float4*)&ms[rg * 2 + rr][0])[kc];
        }
        SAGE_STEP(0, x, WtR4, WtL4, 16)
        SAGE_STEP(1, y, WtR4, WtL4, 16)
        SAGE_STEP(2, z, WtR4, WtL4, 16)
        SAGE_STEP(3, w, WtR4, WtL4, 16)
    }

    float4 b4 = ((const float4*)bl)[cg];
#pragma unroll
    for (int rr = 0; rr < 2; ++rr) {
        int n = base + rg * 2 + rr;
        if (n < nNodes) {
            float4 o;
            o.x = acc[rr][0] + b4.x;
            o.y = acc[rr][1] + b4.y;
            o.z = acc[rr][2] + b4.z;
            o.w = acc[rr][3] + b4.w;
            ((float4*)z)[(long long)n * 16 + cg] = o;
        }
    }
}

// ---------------- decoder: out = z @ W_dec^T + b_dec (R9 verbatim) ----------------
__launch_bounds__(256)
__global__ void k_dec(const float* __restrict__ z, const float* __restrict__ Wt,
                      const float* __restrict__ b,
                      float* __restrict__ out, int nNodes) {
    __shared__ float zs[32][64];
    int tid = threadIdx.x;
    int base = blockIdx.x * 32;

    for (int i = tid; i < 32 * 16; i += 256) {
        int row = i >> 4, col4 = i & 15;
        int n = base + row;
        float4 zv = make_float4(0.f, 0.f, 0.f, 0.f);
        if (n < nNodes) zv = ((const float4*)z)[(long long)n * 16 + col4];
        ((float4*)&zs[row][0])[col4] = zv;
    }
    __syncthreads();

    int cg = tid & 31;
    int rg = tid >> 5;
    float acc[4][4];
#pragma unroll
    for (int rr = 0; rr < 4; ++rr)
#pragma unroll
        for (int cc = 0; cc < 4; ++cc) acc[rr][cc] = 0.f;

    const float4* Wt4 = (const float4*)Wt;

    for (int kc = 0; kc < 16; ++kc) {
        float4 zv[4];
#pragma unroll
        for (int rr = 0; rr < 4; ++rr)
            zv[rr] = ((const float4*)&zs[rg * 4 + rr][0])[kc];
#define DEC_STEP(J, COMP)                                                  \
        {                                                                  \
            float4 w4 = Wt4[(kc * 4 + J) * 32 + cg];                       \
            _Pragma("unroll")                                              \
            for (int rr = 0; rr < 4; ++rr) {                               \
                float zj = zv[rr].COMP;                                    \
                acc[rr][0] += zj * w4.x;                                   \
                acc[rr][1] += zj * w4.y;                                   \
                acc[rr][2] += zj * w4.z;                                   \
                acc[rr][3] += zj * w4.w;                                   \
            }                                                              \
        }
        DEC_STEP(0, x)
        DEC_STEP(1, y)
        DEC_STEP(2, z)
        DEC_STEP(3, w)
#undef DEC_STEP
    }

    float4 b4 = ((const float4*)b)[cg];
#pragma unroll
    for (int rr = 0; rr < 4; ++rr) {
        int n = base + rg * 4 + rr;
        if (n < nNodes) {
            float4 o;
            o.x = acc[rr][0] + b4.x;
            o.y = acc[rr][1] + b4.y;
            o.z = acc[rr][2] + b4.z;
            o.w = acc[rr][3] + b4.w;
            ((float4*)out)[(long long)n * 32 + cg] = o;
        }
    }
}

extern "C" void kernel_launch(void* const* d_in, const int* in_sizes, int n_in,
                              void* d_out, int out_size, void* d_ws, size_t ws_size,
                              hipStream_t stream) {
    const float* x    = (const float*)d_in[0];
    const int*   ei   = (const int*)d_in[1];   // int32 on device
    const float* W1l  = (const float*)d_in[2];
    const float* b1l  = (const float*)d_in[3];
    const float* W1r  = (const float*)d_in[4];
    const float* W2l  = (const float*)d_in[5];
    const float* b2l  = (const float*)d_in[6];
    const float* W2r  = (const float*)d_in[7];
    const float* Wdec = (const float*)d_in[8];
    const float* bdec = (const float*)d_in[9];

    const int N = in_sizes[0] / 128;
    const int E = in_sizes[1] / 2;
    const int nb = (N + 255) / 256;

    const int* src = ei;
    const int* dst = ei + E;

    // ws: [float Wt: wt1l 16384 | wt1r 16384 | wt2l 8192 | wt2r 8192 | wtdec 8192]
    //     [int: adj E | deg N | cur N | off N | bs nb]
    float* wsf   = (float*)d_ws;
    float* wt1l  = wsf;
    float* wt1r  = wt1l + 16384;
    float* wt2l  = wt1r + 16384;
    float* wt2r  = wt2l + 8192;
    float* wtdec = wt2r + 8192;
    int*   adj   = (int*)(wtdec + 8192);
    int*   deg   = adj + E;
    int*   cur   = deg + N;
    int*   off   = cur + N;
    int*   bs    = off + N;

    // d_out: x_recon [N*128 f32] | z [N*64 f32]. Park fp16 tensors in the
    // x_recon region (decoder overwrites it last):
    //   xh = fp16(x): first N*64 floats; hb = fp16(h): next N*64 floats.
    float*          outp = (float*)d_out;
    float*          z    = outp + (long long)N * 128;
    float*          xrec = outp;
    unsigned short* xh   = (unsigned short*)outp;
    unsigned*       hbW  = (unsigned*)(outp + (long long)N * 64);
    unsigned short* hb   = (unsigned short*)hbW;

    // weight transposes (merged) + x -> fp16
    k_tw5<<<(57344 + 255) / 256, 256, 0, stream>>>(W1l, W1r, W2l, W2r, Wdec,
                                                   wt1l, wt1r, wt2l, wt2r, wtdec);
    k_cvt<<<(N * 32 + 255) / 256, 256, 0, stream>>>(x, (unsigned*)xh, N * 32);

    hipMemsetAsync(deg, 0, (size_t)2 * N * sizeof(int), stream);

    k_deg  <<<(E + 255) / 256, 256, 0, stream>>>(dst, deg, E, N);
    k_scan1<<<nb, 256, 0, stream>>>(deg, off, bs, N);
    k_scan2<<<1, 512, 0, stream>>>(bs, nb);
    k_scan3<<<nb, 256, 0, stream>>>(off, bs, N);
    k_fill <<<(E + 255) / 256, 256, 0, stream>>>(src, dst, off, cur, adj, E, N);

    const int nblk = (N + 31) / 32;
    k_sage1<<<nblk, 256, 0, stream>>>(x, xh, adj, off, deg, wt1l, b1l, wt1r, hbW, N);
    k_sage2<<<nblk, 256, 0, stream>>>(hb, adj, off, deg, wt2l, b2l, wt2r, z, N);
    k_dec  <<<nblk, 256, 0, stream>>>(z, wtdec, bdec, xrec, N);
}